// Round 1
// baseline (111.954 us; speedup 1.0000x reference)
//
#include <hip/hip_runtime.h>

typedef unsigned short u16;
typedef __attribute__((ext_vector_type(8))) short short8;
typedef __attribute__((ext_vector_type(4))) float f32x4;

#define INVT 14.285714285714286f  // 1 / 0.07

__device__ __forceinline__ u16 f2bf(float f) {
  union { float f; unsigned u; } v; v.f = f;
  unsigned u = v.u;
  u += 0x7fffu + ((u >> 16) & 1u);  // round-to-nearest-even
  return (u16)(u >> 16);
}
__device__ __forceinline__ float bf2f(u16 h) {
  union { unsigned u; float f; } v; v.u = ((unsigned)h) << 16;
  return v.f;
}

// Kernel 1: normalize rows (fp32), cast to bf16, and compute per-row
// diag term d_i = exp((||f̂_i||^2 - 1)/T) and positive-pair dot pos_i.
__global__ void norm_kernel(const float* __restrict__ f1, const float* __restrict__ f2,
                            u16* __restrict__ F, float* __restrict__ dvec,
                            float* __restrict__ pos, int N) {
  int i = blockIdx.x;
  int l = threadIdx.x;  // 64 threads = 1 wave; 2 elements/thread
  const float* a = f1 + (size_t)i * 128;
  const float* b = f2 + (size_t)i * 128;
  float a0 = a[l], a1 = a[l + 64];
  float b0 = b[l], b1 = b[l + 64];
  float sa = a0 * a0 + a1 * a1;
  float sb = b0 * b0 + b1 * b1;
#pragma unroll
  for (int o = 32; o; o >>= 1) { sa += __shfl_xor(sa, o); sb += __shfl_xor(sb, o); }
  float ia = 1.0f / fmaxf(sqrtf(sa), 1e-12f);
  float ib = 1.0f / fmaxf(sqrtf(sb), 1e-12f);
  u16 ba0 = f2bf(a0 * ia), ba1 = f2bf(a1 * ia);
  u16 bb0 = f2bf(b0 * ib), bb1 = f2bf(b1 * ib);
  u16* Fa = F + (size_t)i * 128;
  u16* Fb = F + (size_t)(i + N) * 128;
  Fa[l] = ba0; Fa[l + 64] = ba1;
  Fb[l] = bb0; Fb[l + 64] = bb1;
  // self/cross dots of the bf16-rounded values (what the MFMA will see)
  float fa0 = bf2f(ba0), fa1 = bf2f(ba1);
  float fb0 = bf2f(bb0), fb1 = bf2f(bb1);
  float s1 = fa0 * fa0 + fa1 * fa1;
  float s2 = fb0 * fb0 + fb1 * fb1;
  float cr = fa0 * fb0 + fa1 * fb1;
#pragma unroll
  for (int o = 32; o; o >>= 1) {
    s1 += __shfl_xor(s1, o); s2 += __shfl_xor(s2, o); cr += __shfl_xor(cr, o);
  }
  if (l == 0) {
    dvec[i]     = __expf((s1 - 1.0f) * INVT);
    dvec[i + N] = __expf((s2 - 1.0f) * INVT);
    pos[i] = cr;
    pos[i + N] = cr;
  }
}

__device__ __forceinline__ void glds16(const u16* g, u16* l) {
  __builtin_amdgcn_global_load_lds((const __attribute__((address_space(1))) void*)g,
                                   (__attribute__((address_space(3))) void*)l,
                                   16, 0, 0);
}

// Kernel 2: per 128x128 tile of S = F F^T, compute exp((s-1)/T) and reduce
// over tile ROWS (== row-sum partials by symmetry of S); write P[bi][col].
__global__ __launch_bounds__(256, 2) void gemm_exp_kernel(const u16* __restrict__ F,
                                                          float* __restrict__ P,
                                                          int TWO_N) {
  __shared__ __align__(16) u16 At[128 * 128];  // 32 KB, XOR-swizzled granules
  __shared__ __align__(16) u16 Bt[128 * 128];  // 32 KB
  __shared__ float colsum[128];
  const int tid = threadIdx.x;
  const int wave = tid >> 6, lane = tid & 63;
  const int bi = blockIdx.x, bj = blockIdx.y;
  const u16* Ab = F + (size_t)bi * (128 * 128);  // rows are K-contiguous: tile = 32 KB slab
  const u16* Bb = F + (size_t)bj * (128 * 128);
  if (tid < 128) colsum[tid] = 0.0f;
  // Stage both tiles via global_load_lds (16B/lane, wave-uniform LDS base).
  // LDS granule (r,c) holds global granule (r, c ^ (r&7)) -> gg = g ^ ((g>>4)&7).
#pragma unroll
  for (int t = 0; t < 8; ++t) {
    int chunk = wave * 8 + t;          // 32 chunks x 64 lanes x 16B = 32 KB
    int g = chunk * 64 + lane;
    int gg = g ^ ((g >> 4) & 7);
    glds16(Ab + (size_t)gg * 8, &At[chunk * 512]);
    glds16(Bb + (size_t)gg * 8, &Bt[chunk * 512]);
  }
  __syncthreads();

  const int wr = wave >> 1, wc = wave & 1;  // 2x2 waves, each 64x64
  const int q = lane >> 4, m = lane & 15;
  f32x4 acc[4][4];
#pragma unroll
  for (int fr = 0; fr < 4; ++fr)
#pragma unroll
    for (int cf = 0; cf < 4; ++cf) acc[fr][cf] = (f32x4)(0.0f);

#pragma unroll
  for (int ks = 0; ks < 4; ++ks) {
    const int c = ks * 4 + q;  // k-granule index (8 bf16 per granule)
    short8 av[4], bv[4];
#pragma unroll
    for (int fr = 0; fr < 4; ++fr) {
      int r = wr * 64 + fr * 16 + m;
      av[fr] = *(const short8*)&At[r * 128 + ((c ^ (r & 7)) * 8)];
    }
#pragma unroll
    for (int cf = 0; cf < 4; ++cf) {
      int r = wc * 64 + cf * 16 + m;
      bv[cf] = *(const short8*)&Bt[r * 128 + ((c ^ (r & 7)) * 8)];
    }
#pragma unroll
    for (int fr = 0; fr < 4; ++fr)
#pragma unroll
      for (int cf = 0; cf < 4; ++cf)
        acc[fr][cf] = __builtin_amdgcn_mfma_f32_16x16x32_bf16(av[fr], bv[cf], acc[fr][cf], 0, 0, 0);
  }

  // Epilogue: exp, then COLUMN sums (S symmetric => col sums == row sums).
  // C-layout: col = m, row = q*4 + reg. Sum over fr+reg locally, quads via shfl.
#pragma unroll
  for (int cf = 0; cf < 4; ++cf) {
    float cs = 0.0f;
#pragma unroll
    for (int fr = 0; fr < 4; ++fr)
#pragma unroll
      for (int r = 0; r < 4; ++r)
        cs += __expf((acc[fr][cf][r] - 1.0f) * INVT);
    cs += __shfl_xor(cs, 16);
    cs += __shfl_xor(cs, 32);
    if (q == 0) atomicAdd(&colsum[wc * 64 + cf * 16 + m], cs);
  }
  __syncthreads();
  if (tid < 128) P[(size_t)bi * TWO_N + (size_t)bj * 128 + tid] = colsum[tid];
}

// Kernel 3: E_i = sum_b P[b][i]; term_i = (pos_i-1)/T - log(E_i - d_i); block partials.
__global__ void rowterm_kernel(const float* __restrict__ P, const float* __restrict__ dvec,
                               const float* __restrict__ pos, float* __restrict__ bsum,
                               int TWO_N, int NB) {
  int i = blockIdx.x * 128 + threadIdx.x;
  float e = 0.0f;
  for (int b = 0; b < NB; ++b) e += P[(size_t)b * TWO_N + i];
  float term = (pos[i] - 1.0f) * INVT - logf(e - dvec[i]);
#pragma unroll
  for (int o = 32; o; o >>= 1) term += __shfl_xor(term, o);
  __shared__ float s2[2];
  if ((threadIdx.x & 63) == 0) s2[threadIdx.x >> 6] = term;
  __syncthreads();
  if (threadIdx.x == 0) bsum[blockIdx.x] = s2[0] + s2[1];
}

// Kernel 4: final scalar. Writes (not accumulates) d_out -> safe vs 0xAA poison.
__global__ void final_kernel(const float* __restrict__ bsum, float* __restrict__ out,
                             int n, float scale) {
  float v = (threadIdx.x < n) ? bsum[threadIdx.x] : 0.0f;
#pragma unroll
  for (int o = 32; o; o >>= 1) v += __shfl_xor(v, o);
  if (threadIdx.x == 0) out[0] = v * scale;
}

extern "C" void kernel_launch(void* const* d_in, const int* in_sizes, int n_in,
                              void* d_out, int out_size, void* d_ws, size_t ws_size,
                              hipStream_t stream) {
  const float* f1 = (const float*)d_in[0];
  const float* f2 = (const float*)d_in[1];
  const int N = in_sizes[0] / 128;  // 4096
  const int TWO_N = 2 * N;          // 8192
  const int NB = TWO_N / 128;       // 64

  char* ws = (char*)d_ws;
  u16*   F    = (u16*)ws;                                   // 2N*128 bf16 = 2 MB
  float* dvec = (float*)(ws + (size_t)TWO_N * 128 * 2);     // 2N f32
  float* pos  = dvec + TWO_N;                               // 2N f32
  float* P    = pos + TWO_N;                                // NB * 2N f32 = 2 MB
  float* bsum = P + (size_t)NB * TWO_N;                     // NB f32

  norm_kernel<<<N, 64, 0, stream>>>(f1, f2, F, dvec, pos, N);
  gemm_exp_kernel<<<dim3(NB, NB), 256, 0, stream>>>(F, P, TWO_N);
  rowterm_kernel<<<NB, 128, 0, stream>>>(P, dvec, pos, bsum, TWO_N, NB);
  final_kernel<<<1, 64, 0, stream>>>(bsum, (float*)d_out, NB, -1.0f / (float)TWO_N);
}

// Round 2
// 89.347 us; speedup vs baseline: 1.2530x; 1.2530x over previous
//
#include <hip/hip_runtime.h>

typedef unsigned short u16;
typedef __attribute__((ext_vector_type(8))) short short8;
typedef __attribute__((ext_vector_type(4))) float f32x4;

#define INVT 14.285714285714286f  // 1 / 0.07

__device__ __forceinline__ u16 f2bf(float f) {
  union { float f; unsigned u; } v; v.f = f;
  unsigned u = v.u;
  u += 0x7fffu + ((u >> 16) & 1u);  // round-to-nearest-even
  return (u16)(u >> 16);
}
__device__ __forceinline__ float bf2f(u16 h) {
  union { unsigned u; float f; } v; v.u = ((unsigned)h) << 16;
  return v.f;
}

// Kernel 1: normalize rows (fp32), cast to bf16; per-row diag term
// d_i = exp((||f̂_i||^2 - 1)/T) and positive-pair dot pos_i.
// Also zeroes E[8192] (2 floats per block) so the gemm atomics start clean.
__global__ void norm_kernel(const float* __restrict__ f1, const float* __restrict__ f2,
                            u16* __restrict__ F, float* __restrict__ dvec,
                            float* __restrict__ pos, float* __restrict__ E, int N) {
  int i = blockIdx.x;
  int l = threadIdx.x;  // 64 threads = 1 wave; 2 elements/thread
  if (l < 2) E[2 * i + l] = 0.0f;  // 4096 blocks x 2 = 8192
  const float* a = f1 + (size_t)i * 128;
  const float* b = f2 + (size_t)i * 128;
  float a0 = a[l], a1 = a[l + 64];
  float b0 = b[l], b1 = b[l + 64];
  float sa = a0 * a0 + a1 * a1;
  float sb = b0 * b0 + b1 * b1;
#pragma unroll
  for (int o = 32; o; o >>= 1) { sa += __shfl_xor(sa, o); sb += __shfl_xor(sb, o); }
  float ia = 1.0f / fmaxf(sqrtf(sa), 1e-12f);
  float ib = 1.0f / fmaxf(sqrtf(sb), 1e-12f);
  u16 ba0 = f2bf(a0 * ia), ba1 = f2bf(a1 * ia);
  u16 bb0 = f2bf(b0 * ib), bb1 = f2bf(b1 * ib);
  u16* Fa = F + (size_t)i * 128;
  u16* Fb = F + (size_t)(i + N) * 128;
  Fa[l] = ba0; Fa[l + 64] = ba1;
  Fb[l] = bb0; Fb[l + 64] = bb1;
  // self/cross dots of the bf16-rounded values (what the MFMA will see)
  float fa0 = bf2f(ba0), fa1 = bf2f(ba1);
  float fb0 = bf2f(bb0), fb1 = bf2f(bb1);
  float s1 = fa0 * fa0 + fa1 * fa1;
  float s2 = fb0 * fb0 + fb1 * fb1;
  float cr = fa0 * fb0 + fa1 * fb1;
#pragma unroll
  for (int o = 32; o; o >>= 1) {
    s1 += __shfl_xor(s1, o); s2 += __shfl_xor(s2, o); cr += __shfl_xor(cr, o);
  }
  if (l == 0) {
    dvec[i]     = __expf((s1 - 1.0f) * INVT);
    dvec[i + N] = __expf((s2 - 1.0f) * INVT);
    pos[i] = cr;
    pos[i + N] = cr;
  }
}

__device__ __forceinline__ void glds16(const u16* g, u16* l) {
  __builtin_amdgcn_global_load_lds((const __attribute__((address_space(1))) void*)g,
                                   (__attribute__((address_space(3))) void*)l,
                                   16, 0, 0);
}

// Kernel 2 (symmetric): for tile pair (bi<=bj) of S = F F^T, compute
// exp((s-1)/T); accumulate tile column-sums into E[bj*128+*] and (off-diag)
// tile row-sums into E[bi*128+*]. S symmetric => this covers every (i,j) once.
__global__ __launch_bounds__(256, 2) void gemm_exp_kernel(const u16* __restrict__ F,
                                                          float* __restrict__ E) {
  __shared__ __align__(16) u16 At[128 * 128];  // 32 KB, XOR-swizzled granules
  __shared__ __align__(16) u16 Bt[128 * 128];  // 32 KB
  __shared__ float colsum[128];
  __shared__ float rowsum[128];
  const int tid = threadIdx.x;
  const int wave = tid >> 6, lane = tid & 63;
  // triangular decode: p -> (bj=r, bi=c<=r)
  int p = blockIdx.x;
  int r = (int)((sqrtf(8.0f * (float)p + 1.0f) - 1.0f) * 0.5f);
  while ((r + 1) * (r + 2) / 2 <= p) ++r;
  while (r * (r + 1) / 2 > p) --r;
  const int bj = r, bi = p - r * (r + 1) / 2;
  const u16* Ab = F + (size_t)bi * (128 * 128);  // rows K-contiguous: tile = 32 KB slab
  const u16* Bb = F + (size_t)bj * (128 * 128);
  if (tid < 128) { colsum[tid] = 0.0f; rowsum[tid] = 0.0f; }
  // Stage tiles via global_load_lds (16B/lane, wave-uniform LDS base).
  // LDS granule (r,c) holds global granule (r, c ^ (r&7)) -> gg = g ^ ((g>>4)&7).
#pragma unroll
  for (int t = 0; t < 8; ++t) {
    int chunk = wave * 8 + t;          // 32 chunks x 64 lanes x 16B = 32 KB
    int g = chunk * 64 + lane;
    int gg = g ^ ((g >> 4) & 7);
    glds16(Ab + (size_t)gg * 8, &At[chunk * 512]);
    glds16(Bb + (size_t)gg * 8, &Bt[chunk * 512]);
  }
  __syncthreads();

  const int wr = wave >> 1, wc = wave & 1;  // 2x2 waves, each 64x64
  const int q = lane >> 4, m = lane & 15;
  f32x4 acc[4][4];
#pragma unroll
  for (int fr = 0; fr < 4; ++fr)
#pragma unroll
    for (int cf = 0; cf < 4; ++cf) acc[fr][cf] = (f32x4)(0.0f);

#pragma unroll
  for (int ks = 0; ks < 4; ++ks) {
    const int c = ks * 4 + q;  // k-granule index (8 bf16 per granule)
    short8 av[4], bv[4];
#pragma unroll
    for (int fr = 0; fr < 4; ++fr) {
      int rr = wr * 64 + fr * 16 + m;
      av[fr] = *(const short8*)&At[rr * 128 + ((c ^ (rr & 7)) * 8)];
    }
#pragma unroll
    for (int cf = 0; cf < 4; ++cf) {
      int rr = wc * 64 + cf * 16 + m;
      bv[cf] = *(const short8*)&Bt[rr * 128 + ((c ^ (rr & 7)) * 8)];
    }
#pragma unroll
    for (int fr = 0; fr < 4; ++fr)
#pragma unroll
      for (int cf = 0; cf < 4; ++cf)
        acc[fr][cf] = __builtin_amdgcn_mfma_f32_16x16x32_bf16(av[fr], bv[cf], acc[fr][cf], 0, 0, 0);
  }

  // Epilogue. C-layout: col = m (within frag), row = q*4 + reg.
  float cs[4] = {0.f, 0.f, 0.f, 0.f};
  float rs[16];
#pragma unroll
  for (int i = 0; i < 16; ++i) rs[i] = 0.f;
#pragma unroll
  for (int cf = 0; cf < 4; ++cf)
#pragma unroll
    for (int fr = 0; fr < 4; ++fr)
#pragma unroll
      for (int rg = 0; rg < 4; ++rg) {
        float e = __expf((acc[fr][cf][rg] - 1.0f) * INVT);
        cs[cf] += e;
        rs[fr * 4 + rg] += e;
      }
  // column sums: reduce across quads (rows) -> q==0 holds col total
#pragma unroll
  for (int cf = 0; cf < 4; ++cf) {
    cs[cf] += __shfl_xor(cs[cf], 16);
    cs[cf] += __shfl_xor(cs[cf], 32);
    if (q == 0) atomicAdd(&colsum[wc * 64 + cf * 16 + m], cs[cf]);
  }
  // row sums (off-diagonal tiles only): reduce across m within each quad
  if (bi != bj) {
#pragma unroll
    for (int i = 0; i < 16; ++i) {
#pragma unroll
      for (int o = 1; o < 16; o <<= 1) rs[i] += __shfl_xor(rs[i], o);
    }
    if (m == 0) {
#pragma unroll
      for (int i = 0; i < 16; ++i)
        atomicAdd(&rowsum[wr * 64 + (i >> 2) * 16 + q * 4 + (i & 3)], rs[i]);
    }
  }
  __syncthreads();
  if (tid < 128) {
    atomicAdd(&E[bj * 128 + tid], colsum[tid]);
    if (bi != bj) atomicAdd(&E[bi * 128 + tid], rowsum[tid]);
  }
}

// Kernel 3: single block; term_i = (pos_i-1)/T - log(E_i - d_i); mean; write out.
__global__ void finish_kernel(const float* __restrict__ E, const float* __restrict__ dvec,
                              const float* __restrict__ pos, float* __restrict__ out,
                              int TWO_N, float scale) {
  float t = 0.0f;
  for (int i = threadIdx.x; i < TWO_N; i += 1024)
    t += (pos[i] - 1.0f) * INVT - logf(E[i] - dvec[i]);
#pragma unroll
  for (int o = 32; o; o >>= 1) t += __shfl_xor(t, o);
  __shared__ float wsum[16];
  int wave = threadIdx.x >> 6, lane = threadIdx.x & 63;
  if (lane == 0) wsum[wave] = t;
  __syncthreads();
  if (threadIdx.x == 0) {
    float s = 0.0f;
#pragma unroll
    for (int k = 0; k < 16; ++k) s += wsum[k];
    out[0] = s * scale;
  }
}

extern "C" void kernel_launch(void* const* d_in, const int* in_sizes, int n_in,
                              void* d_out, int out_size, void* d_ws, size_t ws_size,
                              hipStream_t stream) {
  const float* f1 = (const float*)d_in[0];
  const float* f2 = (const float*)d_in[1];
  const int N = in_sizes[0] / 128;  // 4096
  const int TWO_N = 2 * N;          // 8192
  const int NB = TWO_N / 128;       // 64
  const int NTILES = NB * (NB + 1) / 2;  // 2080

  char* ws = (char*)d_ws;
  u16*   F    = (u16*)ws;                                   // 2N*128 bf16 = 2 MB
  float* dvec = (float*)(ws + (size_t)TWO_N * 128 * 2);     // 2N f32
  float* pos  = dvec + TWO_N;                               // 2N f32
  float* E    = pos + TWO_N;                                // 2N f32

  norm_kernel<<<N, 64, 0, stream>>>(f1, f2, F, dvec, pos, E, N);
  gemm_exp_kernel<<<NTILES, 256, 0, stream>>>(F, E);
  finish_kernel<<<1, 1024, 0, stream>>>(E, dvec, pos, (float*)d_out, TWO_N,
                                        -1.0f / (float)TWO_N);
}